// Round 1
// 111.316 us; speedup vs baseline: 1.0205x; 1.0205x over previous
//
#include <hip/hip_runtime.h>
#include <stdint.h>

typedef unsigned long long u64;

// Problem constants (from reference file)
constexpr int B_ = 4;
constexpr int N_ = 160;
constexpr int T_ = 512;
constexpr int W_ = T_ / 64;   // 8 u64 words per 512-bit row

// ---------------------------------------------------------------------------
// Kernel 1: gather + bit-pack tag rows AND pack M AND zero the accumulators.
// grid = B*N + B blocks, 64 threads.
//   blocks [0, B*N): pack emb[preds[row]] -> tags[row]
//   blocks [B*N, B*N+B): pack Mf[b] -> Mp[b]; block B*N also zeroes acc/cnt.
// ---------------------------------------------------------------------------
__global__ __launch_bounds__(64) void pack_all(const float* __restrict__ emb,
                                               const int* __restrict__ preds,
                                               const float* __restrict__ Mf,
                                               u64* __restrict__ tags,
                                               u64* __restrict__ Mp,
                                               double* __restrict__ accD,
                                               int* __restrict__ cnt) {
    int row  = blockIdx.x;
    int lane = threadIdx.x;
    if (row < B_ * N_) {
        const float* src = emb + (long long)preds[row] * T_;
#pragma unroll
        for (int w = 0; w < W_; ++w) {
            u64 m = __ballot(src[w * 64 + lane] != 0.0f);
            if (lane == 0) tags[(long long)row * W_ + w] = m;
        }
    } else {
        int b = row - B_ * N_;
        const float* src = Mf + (long long)b * T_;
#pragma unroll
        for (int w = 0; w < W_; ++w) {
            u64 m = __ballot(src[w * 64 + lane] != 0.0f);
            if (lane == 0) Mp[b * W_ + w] = m;
        }
        if (b == 0 && lane == 0) { accD[0] = 0.0; cnt[0] = 0; }
    }
}

// ---------------------------------------------------------------------------
// Kernel 2: fully fused main. grid = (N, B), 256 threads.
// Per block (k,b), all in LDS:
//   Tsh   <- tags (transposed [w][r], LD=161)
//   bT    = M & ~tags             (built from Tsh before it's overwritten)
//   suffix OR-scan bounded at k   (ping-pong U/V, first step reads Tsh)
//   prefix OR-scan over all rows  (ping-pong Tsh<->freebuf, result in Tsh)
//   aw[i] = M & ~pre_i & ~suf[i+1]   (i <= k), written into free scratch
//   cU[k] = popc(M & ~P[k]); Mc = popc(M)+1   (tid 0, in-LDS)
//   pair sweep over i in [0,k], j in (k, N): identical to previous version
//   block value -> atomicAdd(double acc); last block (atomic counter) writes out
// Eliminates pack_scan + finalize kernels and the P/cU/Mc/partials round-trips.
// ---------------------------------------------------------------------------
__global__ __launch_bounds__(256) void lambda_main(const u64* __restrict__ tags,
                                                   const u64* __restrict__ Mp,
                                                   const float* __restrict__ scores,
                                                   double* __restrict__ accD,
                                                   int* __restrict__ cnt,
                                                   float* __restrict__ out) {
    constexpr int LD = N_ + 1;        // 161, pad to break bank strides
    __shared__ u64 Tsh[W_ * LD];      // tags, later prefix result
    __shared__ u64 U[W_ * LD];        // scan scratch
    __shared__ u64 V[W_ * LD];        // scan scratch
    __shared__ u64 bT[W_ * LD];       // M & ~tags
    __shared__ u64 Msh[W_];
    __shared__ float scoresL[N_];
    __shared__ float redF[4];
    __shared__ float cUsh, Mcsh;

    const int k   = blockIdx.x;
    const int b   = blockIdx.y;
    const int tid = threadIdx.x;

    if (tid < W_)  Msh[tid]     = Mp[b * W_ + tid];
    if (tid < N_)  scoresL[tid] = scores[b * N_ + tid];

    // load tags (coalesced) -> transposed LDS
    for (int x = tid; x < W_ * N_; x += 256) {
        int r = x >> 3, w = x & 7;
        Tsh[w * LD + r] = tags[(long long)b * N_ * W_ + x];
    }
    __syncthreads();

    // bT for all rows (reads Tsh; Tsh first overwritten only after >=1 barrier)
    for (int x = tid; x < W_ * N_; x += 256) {
        int r = x >> 3, w = x & 7;
        bT[w * LD + r] = Msh[w] & ~Tsh[w * LD + r];
    }

    // suffix OR-scan bounded at k: result[r] = OR tags[r..k-1], rows r<k.
    // First step reads Tsh (preserved), then ping-pongs U/V.
    u64* rd = Tsh;
    u64* wr = U;
    for (int d = 1; d < k; d <<= 1) {
        for (int x = tid; x < W_ * k; x += 256) {
            int r = x >> 3, w = x & 7;
            u64 v = rd[w * LD + r];
            if (r + d < k) v |= rd[w * LD + r + d];
            wr[w * LD + r] = v;
        }
        __syncthreads();
        rd = wr;
        wr = (rd == U) ? V : U;
    }
    u64* suf = rd;        // rows 1..k-1 valid when k>=2; aliases Tsh iff k<=1 (never read then)
    u64* freebuf = wr;    // scratch distinct from suf

    // prefix OR-scan over all rows, ping-pong Tsh <-> freebuf (8 steps -> result in Tsh)
    u64* prd = Tsh;
    u64* pwr = freebuf;
    for (int d = 1; d < N_; d <<= 1) {
        for (int x = tid; x < W_ * N_; x += 256) {
            int r = x >> 3, w = x & 7;
            u64 v = prd[w * LD + r];
            if (r >= d) v |= prd[w * LD + r - d];
            pwr[w * LD + r] = v;
        }
        __syncthreads();
        u64* t = prd; prd = pwr; pwr = t;
    }
    // prd == Tsh holds P[r] = OR tags[0..r]; pwr == freebuf is free scratch

    // build aw rows 0..k into the free scratch
    u64* aw = pwr;
    for (int x = tid; x < W_ * (k + 1); x += 256) {
        int i = x >> 3, w = x & 7;
        u64 pre;
        if (i == 1) pre = 0ull;
        else {
            int sr = (i == 0) ? (N_ - 2) : (i - 2);
            pre = prd[w * LD + sr];
        }
        u64 sv = (i + 1 < k) ? suf[w * LD + i + 1] : 0ull;
        aw[w * LD + i] = Msh[w] & ~pre & ~sv;
    }
    if (tid == 0) {
        int c = 0, cm = 0;
#pragma unroll
        for (int w = 0; w < W_; ++w) {
            c  += __popcll(Msh[w] & ~prd[w * LD + k]);
            cm += __popcll(Msh[w]);
        }
        cUsh = (float)c;
        Mcsh = (float)(cm + 1);
    }
    __syncthreads();

    // pair sweep: p = tid + 256*c over i in [0,k], j in [k+1, N)
    const int m = N_ - 1 - k;         // number of j values
    float accLam = 0.0f, accC = 0.0f;
    if (m > 0) {
        const int npairs = (k + 1) * m;
        if (tid < npairs) {
            int cntp = (npairs - tid + 255) >> 8;
            int i   = tid / m;
            int jj  = tid - i * m;
            const int di = 256 / m;
            const int rj = 256 - di * m;
            for (int c = 0; c < cntp; ++c) {
                const int j = k + 1 + jj;
                int cc = 0;
#pragma unroll
                for (int w = 0; w < W_; ++w)
                    cc += __popcll(aw[w * LD + i] & bT[w * LD + j]);
                float lam = 1.0f / (1.0f + __expf(scoresL[i] - scoresL[j]));
                accLam += lam;
                accC   += lam * (float)cc;
                i += di; jj += rj;
                if (jj >= m) { jj -= m; ++i; }
            }
        }
    }

    float val = cUsh * accLam - accC;
    for (int off = 32; off >= 1; off >>= 1) val += __shfl_down(val, off, 64);
    if ((tid & 63) == 0) redF[tid >> 6] = val;
    __syncthreads();
    if (tid == 0) {
        float s = redF[0] + redF[1] + redF[2] + redF[3];
        float invlog = 1.0f / log2f((float)(k + 2));
        double v = (double)(s * invlog) / (double)Mcsh;
        atomicAdd(accD, v);
        __threadfence();
        int c = atomicAdd(cnt, 1);
        if (c == B_ * N_ - 1) {
            double total = atomicAdd(accD, 0.0);   // all 640 adds complete here
            out[0] = (float)(total / ((double)(N_ + 1) * (double)B_));
        }
    }
}

// ---------------------------------------------------------------------------
extern "C" void kernel_launch(void* const* d_in, const int* in_sizes, int n_in,
                              void* d_out, int out_size, void* d_ws, size_t ws_size,
                              hipStream_t stream) {
    const float* y_scores = (const float*)d_in[0];   // B*N f32
    const float* Mf       = (const float*)d_in[1];   // B*T f32
    const float* emb      = (const float*)d_in[2];   // NUM_API*T f32
    const int*   preds    = (const int*)d_in[3];     // B*N i32
    float* out = (float*)d_out;

    // workspace layout (all 8-byte aligned)
    u64* tags   = (u64*)d_ws;                         // B*N*W
    u64* Mp     = tags + (size_t)B_ * N_ * W_;        // B*W
    double* accD = (double*)(Mp + B_ * W_);           // 1
    int* cnt    = (int*)(accD + 1);                   // 1

    pack_all<<<B_ * N_ + B_, 64, 0, stream>>>(emb, preds, Mf, tags, Mp, accD, cnt);
    dim3 grid(N_, B_);
    lambda_main<<<grid, 256, 0, stream>>>(tags, Mp, y_scores, accD, cnt, out);
}